// Round 1
// baseline (56.623 us; speedup 1.0000x reference)
//
#include <hip/hip_runtime.h>
#include <cmath>

// PlotLine: 8 polylines -> 128x128 Gaussian-splatted images, tanh'd.
// draft[n,i,j] = sum_l px[n,l,i] * py[n,l,j]  (separable Gaussians)
// out = tanh(draft)

constexpr int IMG   = 128;
constexpr int NPTS  = 32;
constexpr int NSEG  = NPTS - 1;       // 31
constexpr int TPL   = 181;            // samples per segment (CMP_NUM=int(128*sqrt(2)))
constexpr int LTOT  = NSEG * TPL;     // 5611
constexpr int CHUNK = 16;             // l's staged in LDS per barrier
constexpr int PIX   = IMG * IMG;      // 16384

// Kernel 1: each block = (L-slice s, image n); produces a full 128x128
// partial-sum tile in acc_out[(s*nimg+n)*PIX + ...]. 256 threads, 8x8
// register tile per thread.
__global__ __launch_bounds__(256, 1)
void plot_partial_kernel(const float* __restrict__ pts,
                         float* __restrict__ acc_out,
                         int per, int nimg)
{
    const int s = blockIdx.x;
    const int n = blockIdx.y;
    const int t = threadIdx.x;

    __shared__ float ptsh[NPTS * 3];
    __shared__ float pxs[CHUNK][IMG];
    __shared__ float pys[CHUNK][IMG];

    if (t < NPTS * 3) ptsh[t] = pts[n * NPTS * 3 + t];
    __syncthreads();

    const int lbase = s * per;
    const int lend  = min(lbase + per, LTOT);

    const int ty = t >> 4;       // 0..15
    const int tx = t & 15;       // 0..15
    const int i0 = ty * 8;       // output row base
    const int j0 = tx * 8;       // output col base

    float acc[8][8];
#pragma unroll
    for (int r = 0; r < 8; ++r)
#pragma unroll
        for (int q = 0; q < 8; ++q) acc[r][q] = 0.0f;

    const float inv_tpl = 1.0f / (float)TPL;
    const float nhl2e   = -0.7213475204444817f;   // -log2(e)/2

    for (int c0 = lbase; c0 < lend; c0 += CHUNK) {
        const int lc = min(CHUNK, lend - c0);

        // ---- profile (exp) phase: thread group ty handles l = c0+ty,
        //      16 threads (tx) cover 256 profile entries, 16 each.
        if (ty < lc) {
            const int   l   = c0 + ty;
            const int   seg = l / TPL;                       // magic-mul
            const float ft  = (float)(l - seg * TPL) * inv_tpl;
            const float* p  = &ptsh[seg * 3];
            const float x = p[0] + ft * (p[3] - p[0]);
            const float y = p[1] + ft * (p[4] - p[1]);
            const float w = p[2] + ft * (p[5] - p[2]);
            const float cf = nhl2e / w;                      // exp(-d2/2w)=2^(d2*cf)
#pragma unroll
            for (int k = 0; k < 8; ++k) {
                const int idx = tx + 16 * k;
                const float d = x - (float)idx;
                pxs[ty][idx] = exp2f(d * d * cf);
            }
#pragma unroll
            for (int k = 0; k < 8; ++k) {
                const int idx = tx + 16 * k;
                const float d = y - (float)idx;
                pys[ty][idx] = exp2f(d * d * cf);
            }
        }
        __syncthreads();

        // ---- rank-1 accumulate phase: 64 FMA + 4 ds_read_b128 per l
#pragma unroll 2
        for (int l = 0; l < lc; ++l) {
            const float4 a0 = *(const float4*)&pxs[l][i0];
            const float4 a1 = *(const float4*)&pxs[l][i0 + 4];
            const float4 b0 = *(const float4*)&pys[l][j0];
            const float4 b1 = *(const float4*)&pys[l][j0 + 4];
            const float av[8] = {a0.x, a0.y, a0.z, a0.w, a1.x, a1.y, a1.z, a1.w};
            const float bv[8] = {b0.x, b0.y, b0.z, b0.w, b1.x, b1.y, b1.z, b1.w};
#pragma unroll
            for (int r = 0; r < 8; ++r)
#pragma unroll
                for (int q = 0; q < 8; ++q)
                    acc[r][q] = fmaf(av[r], bv[q], acc[r][q]);
        }
        __syncthreads();
    }

    float* o = acc_out + ((size_t)(s * nimg + n)) * PIX;
#pragma unroll
    for (int r = 0; r < 8; ++r) {
#pragma unroll
        for (int q = 0; q < 8; q += 4) {
            float4 v = make_float4(acc[r][q], acc[r][q + 1],
                                   acc[r][q + 2], acc[r][q + 3]);
            *(float4*)&o[(i0 + r) * IMG + j0 + q] = v;
        }
    }
}

// Kernel 2: reduce S slices + tanh. Coalesced: thread p sums stride-total.
__global__ __launch_bounds__(256)
void reduce_tanh_kernel(const float* __restrict__ acc_in,
                        float* __restrict__ out, int slices, int total)
{
    const int p = blockIdx.x * 256 + threadIdx.x;
    if (p >= total) return;
    float s = 0.0f;
    for (int i = 0; i < slices; ++i) s += acc_in[(size_t)i * total + p];
    out[p] = tanhf(s);
}

extern "C" void kernel_launch(void* const* d_in, const int* in_sizes, int n_in,
                              void* d_out, int out_size, void* d_ws, size_t ws_size,
                              hipStream_t stream) {
    const float* pts  = (const float*)d_in[0];
    const int    nimg = in_sizes[0] / (NPTS * 3);      // 8
    const int    total = nimg * PIX;                   // 131072
    float*       out  = (float*)d_out;

    // pick slice count from workspace size (target 64 -> 512 blocks)
    int S = 64;
    while (S > 1 && (size_t)S * (size_t)total * sizeof(float) > ws_size) S >>= 1;

    float* accbuf;
    if ((size_t)S * (size_t)total * sizeof(float) <= ws_size) {
        accbuf = (float*)d_ws;
    } else {
        S = 1;                 // degenerate fallback: accumulate in d_out
        accbuf = out;
    }

    const int per = (LTOT + S - 1) / S;
    dim3 g1(S, nimg);
    plot_partial_kernel<<<g1, dim3(256), 0, stream>>>(pts, accbuf, per, nimg);

    const int blocks2 = (total + 255) / 256;
    reduce_tanh_kernel<<<blocks2, dim3(256), 0, stream>>>(accbuf, out, S, total);
}

// Round 2
// 44.648 us; speedup vs baseline: 1.2682x; 1.2682x over previous
//
#include <hip/hip_runtime.h>
#include <hip/hip_bf16.h>
#include <cmath>

// PlotLine: 8 polylines -> 128x128 Gaussian-splatted images, tanh'd.
// draft[n,i,j] = sum_l px[n,l,i] * py[n,l,j]  (separable Gaussians)
// Rank-1-sum == GEMM (M=N=128, K=5611) per image -> bf16 MFMA.

constexpr int IMG   = 128;
constexpr int NPTS  = 32;
constexpr int TPL   = 181;            // samples per segment
constexpr int LTOT  = 31 * TPL;       // 5611
constexpr int PIX   = IMG * IMG;      // 16384
constexpr int KC    = 32;             // K per MFMA chunk

typedef __attribute__((ext_vector_type(8))) short bf16x8;
typedef __attribute__((ext_vector_type(4))) float f32x4;

__device__ inline unsigned short bf16bits(float f) {
    __hip_bfloat16 h = __float2bfloat16(f);
    return *reinterpret_cast<unsigned short*>(&h);
}

// swizzled byte offset of bf16 element [row][k] in a [128][KC] bf16 tile.
// row stride = 64B; XOR bits [5:4] with (row>>1)&3 spreads the 16B slots
// so ds_read_b128 of a 16-row column slice is ~2-way (free) not 8-way.
__device__ inline int swz(int row, int k) {
    return (row * (KC * 2) + k * 2) ^ (((row >> 1) & 3) << 4);
}

__global__ __launch_bounds__(256, 2)
void plot_mfma_kernel(const float* __restrict__ pts,
                      float* __restrict__ acc_out,
                      int per, int nimg)
{
    const int s = blockIdx.x;
    const int n = blockIdx.y;
    const int t = threadIdx.x;

    __shared__ float ptsh[NPTS * 3];
    __shared__ float xk[KC], yk[KC], cfk[KC];
    __shared__ char  pa[128 * KC * 2];   // bf16 [i][k], swizzled
    __shared__ char  pb[128 * KC * 2];   // bf16 [j][k], swizzled

    if (t < NPTS * 3) ptsh[t] = pts[n * NPTS * 3 + t];

    const int lbase = s * per;
    const int lend  = min(lbase + per, LTOT);

    f32x4 acc[4][4];
#pragma unroll
    for (int mi = 0; mi < 4; ++mi)
#pragma unroll
        for (int nj = 0; nj < 4; ++nj) acc[mi][nj] = (f32x4)0.0f;

    const int lid = t & 63;
    const int w   = t >> 6;              // wave 0..3
    const int iq  = (w >> 1) * 64;       // wave quadrant origin (rows)
    const int jq  = (w & 1) * 64;        // (cols)

    // profile-fill mapping: thread owns k-pair fk,fk+1 at 8 i's
    const int fk  = (t & 15) * 2;
    const int fi0 = t >> 4;              // 0..15

    // fragment mapping
    const int frow = lid & 15;
    const int kb   = (lid >> 4) * 8;     // k base within chunk

    const float nhl2e = -0.7213475204444817f;   // -log2(e)/2

    for (int c0 = lbase; c0 < lend; c0 += KC) {
        __syncthreads();   // prev-chunk frag reads done before param rewrite
        if (t < KC) {
            const int l = c0 + t;
            float xv = 65536.0f, yv = 65536.0f, cf = -1.0f;
            if (l < lend) {
                const int   seg = l / TPL;
                const float ft  = (float)(l - seg * TPL) * (1.0f / TPL);
                const float* p  = &ptsh[seg * 3];
                xv = p[0] + ft * (p[3] - p[0]);
                yv = p[1] + ft * (p[4] - p[1]);
                const float wv = p[2] + ft * (p[5] - p[2]);
                cf = nhl2e / wv;         // exp(-d^2/2w) = 2^(d^2*cf)
            }
            xk[t] = xv; yk[t] = yv; cfk[t] = cf;
        }
        __syncthreads();

        // fill pa/pb: 16 exps each per thread, packed b32 writes
        {
            const float x0 = xk[fk],  x1 = xk[fk + 1];
            const float y0 = yk[fk],  y1 = yk[fk + 1];
            const float cA = cfk[fk], cB = cfk[fk + 1];
#pragma unroll
            for (int m = 0; m < 8; ++m) {
                const int   i  = fi0 + 16 * m;
                const float fi = (float)i;
                const float dx0 = fi - x0, dx1 = fi - x1;
                const float dy0 = fi - y0, dy1 = fi - y1;
                const unsigned pav = (unsigned)bf16bits(exp2f(dx0 * dx0 * cA))
                                   | ((unsigned)bf16bits(exp2f(dx1 * dx1 * cB)) << 16);
                const unsigned pbv = (unsigned)bf16bits(exp2f(dy0 * dy0 * cA))
                                   | ((unsigned)bf16bits(exp2f(dy1 * dy1 * cB)) << 16);
                const int off = swz(i, fk);
                *(unsigned*)(pa + off) = pav;
                *(unsigned*)(pb + off) = pbv;
            }
        }
        __syncthreads();

        // MFMA phase: 8 ds_read_b128 + 16 mfma per wave
        bf16x8 af[4], bg[4];
#pragma unroll
        for (int mi = 0; mi < 4; ++mi)
            af[mi] = *(const bf16x8*)(pa + swz(iq + mi * 16 + frow, kb));
#pragma unroll
        for (int nj = 0; nj < 4; ++nj)
            bg[nj] = *(const bf16x8*)(pb + swz(jq + nj * 16 + frow, kb));
#pragma unroll
        for (int mi = 0; mi < 4; ++mi)
#pragma unroll
            for (int nj = 0; nj < 4; ++nj)
                acc[mi][nj] = __builtin_amdgcn_mfma_f32_16x16x32_bf16(
                    af[mi], bg[nj], acc[mi][nj], 0, 0, 0);
    }

    // write fp32 partial tile. D layout: col=lane&15, row=(lane>>4)*4+r
    float* o = acc_out + (size_t)(s * nimg + n) * PIX;
    const int dcol = lid & 15;
    const int drow = (lid >> 4) * 4;
#pragma unroll
    for (int mi = 0; mi < 4; ++mi)
#pragma unroll
        for (int nj = 0; nj < 4; ++nj)
#pragma unroll
            for (int r = 0; r < 4; ++r) {
                const int i = iq + mi * 16 + drow + r;
                const int j = jq + nj * 16 + dcol;
                o[i * IMG + j] = acc[mi][nj][r];
            }
}

// Kernel 2: reduce S slices + tanh. Coalesced.
__global__ __launch_bounds__(256)
void reduce_tanh_kernel(const float* __restrict__ acc_in,
                        float* __restrict__ out, int slices, int total)
{
    const int p = blockIdx.x * 256 + threadIdx.x;
    if (p >= total) return;
    float s = 0.0f;
    for (int i = 0; i < slices; ++i) s += acc_in[(size_t)i * total + p];
    out[p] = tanhf(s);
}

extern "C" void kernel_launch(void* const* d_in, const int* in_sizes, int n_in,
                              void* d_out, int out_size, void* d_ws, size_t ws_size,
                              hipStream_t stream) {
    const float* pts   = (const float*)d_in[0];
    const int    nimg  = in_sizes[0] / (NPTS * 3);   // 8
    const int    total = nimg * PIX;                 // 131072
    float*       out   = (float*)d_out;

    int S = 64;
    while (S > 1 && (size_t)S * (size_t)total * sizeof(float) > ws_size) S >>= 1;

    float* accbuf;
    if ((size_t)S * (size_t)total * sizeof(float) <= ws_size) {
        accbuf = (float*)d_ws;
    } else {
        S = 1;
        accbuf = out;
    }

    const int per = (LTOT + S - 1) / S;
    dim3 g1(S, nimg);
    plot_mfma_kernel<<<g1, dim3(256), 0, stream>>>(pts, accbuf, per, nimg);

    const int blocks2 = (total + 255) / 256;
    reduce_tanh_kernel<<<blocks2, dim3(256), 0, stream>>>(accbuf, out, S, total);
}

// Round 4
// 28.431 us; speedup vs baseline: 1.9916x; 1.5704x over previous
//
#include <hip/hip_runtime.h>
#include <hip/hip_bf16.h>
#include <cmath>

// PlotLine: 8 polylines -> 128x128 Gaussian-splatted images, tanh'd.
// draft[n,i,j] = sum_l exp(-(i-x_l)^2/2w_l) * exp(-(j-y_l)^2/2w_l); out = tanh.
// Single fused kernel, NO workspace. Each block owns one (img, 32x16 tile)
// END-TO-END (full K), so no cross-block reduction (round-3 bug fixed).
// 8 waves split K 8-ways; fragments built in registers from exp2; 8 partials
// reduced via LDS; tanh; store.

constexpr int IMG  = 128;
constexpr int NPTS = 32;
constexpr int TPL  = 181;           // samples per segment
constexpr int LTOT = 31 * TPL;      // 5611
constexpr int KC   = 32;            // K per MFMA chunk
constexpr int NCH  = 176;           // ceil(LTOT/KC) -> 176*32 = 5632 (tail padded)
constexpr int NW   = 8;             // waves per block
constexpr int CPW  = NCH / NW;      // 22 chunks per wave
constexpr int TI   = 32;            // tile rows  (i)
constexpr int TJ   = 16;            // tile cols  (j)

typedef __attribute__((ext_vector_type(8))) short bf16x8;
typedef __attribute__((ext_vector_type(4))) float f32x4;

__device__ inline short bf16bits(float f) {
    __hip_bfloat16 h = __float2bfloat16(f);
    return *reinterpret_cast<short*>(&h);
}

__global__ __launch_bounds__(512, 1)
void plot_fused_kernel(const float* __restrict__ pts, float* __restrict__ out)
{
    const int bx   = blockIdx.x;
    const int img  = bx >> 5;           // 32 tiles per image
    const int tile = bx & 31;
    const int i0   = (tile >> 3) * TI;  // 4 row-tiles
    const int j0   = (tile & 7) * TJ;   // 8 col-tiles

    const int t   = threadIdx.x;
    const int w   = t >> 6;             // wave 0..7
    const int lid = t & 63;

    __shared__ float4 ptsh[NPTS];           // (x, y, width, _)
    __shared__ float4 p4s[NW][KC];          // per-wave l-params: cf, B1x, C0x, B1y
    __shared__ float  c0ys[NW][KC];         // C0y
    __shared__ float  red[NW][TI][TJ + 2];  // epilogue partials (stride 18)

    if (t < NPTS) {
        const float* p = pts + (img * NPTS + t) * 3;
        ptsh[t] = make_float4(p[0], p[1], p[2], 0.0f);
    }
    __syncthreads();

    f32x4 acc0 = (f32x4)0.0f;   // rows i0..i0+15
    f32x4 acc1 = (f32x4)0.0f;   // rows i0+16..i0+31

    const float r0f = (float)(i0 + (lid & 15));
    const float r1f = r0f + 16.0f;
    const float cjf = (float)(j0 + (lid & 15));
    const float r02 = r0f * r0f;
    const float r12 = r1f * r1f;
    const float cj2 = cjf * cjf;
    const int   kb  = (lid >> 4) * 8;       // k base within chunk

    for (int tt = 0; tt < CPW; ++tt) {
        const int c = w + NW * tt;          // this wave's chunk (0..175)

        // ---- params: lanes 0..31 compute quadratic coeffs for l = c*32+lane.
        // exp arg = cf*(r-x)^2 = cf*r^2 + B1x*r + C0x  (2 FMA per element)
        if (lid < KC) {
            const int l = c * KC + lid;
            float cf = 0.0f, b1x = 0.0f, c0x = -1.0e30f, b1y = 0.0f, c0y = -1.0e30f;
            if (l < LTOT) {
                const int   seg = l / TPL;                  // magic-mul
                const float ft  = (float)(l - seg * TPL) * (1.0f / TPL);
                const float4 p0 = ptsh[seg];
                const float4 p1 = ptsh[seg + 1];
                const float x  = p0.x + ft * (p1.x - p0.x);
                const float y  = p0.y + ft * (p1.y - p0.y);
                const float wv = p0.z + ft * (p1.z - p0.z);
                cf  = -0.7213475204444817f / wv;            // -log2(e)/(2w)
                b1x = -2.0f * cf * x;  c0x = cf * x * x;
                b1y = -2.0f * cf * y;  c0y = cf * y * y;
            }
            p4s[w][lid]  = make_float4(cf, b1x, c0x, b1y);
            c0ys[w][lid] = c0y;
        }
        // per-wave LDS, intra-wave producer->consumer: compiler lgkmcnt orders it

        // ---- fragments in registers: 24 exp2 per lane (broadcast param reads)
        bf16x8 a0, a1, b0;
#pragma unroll
        for (int j = 0; j < 8; ++j) {
            const float4 q   = p4s[w][kb + j];
            const float  c0y = c0ys[w][kb + j];
            a0[j] = bf16bits(exp2f(fmaf(q.x, r02, fmaf(q.y, r0f, q.z))));
            a1[j] = bf16bits(exp2f(fmaf(q.x, r12, fmaf(q.y, r1f, q.z))));
            b0[j] = bf16bits(exp2f(fmaf(q.x, cj2, fmaf(q.w, cjf, c0y))));
        }

        acc0 = __builtin_amdgcn_mfma_f32_16x16x32_bf16(a0, b0, acc0, 0, 0, 0);
        acc1 = __builtin_amdgcn_mfma_f32_16x16x32_bf16(a1, b0, acc1, 0, 0, 0);
    }

    // ---- epilogue: 8-wave K reduction via LDS, tanh, store
    // D layout: col = lane&15, row = (lane>>4)*4 + r   (verified round 2)
    const int drow = (lid >> 4) * 4;
    const int dcol = lid & 15;
#pragma unroll
    for (int r = 0; r < 4; ++r) {
        red[w][drow + r][dcol]        = acc0[r];
        red[w][16 + drow + r][dcol]   = acc1[r];
    }
    __syncthreads();

    {
        const int rr = t >> 4;          // 0..31
        const int cc = t & 15;          // 0..15
        float s = 0.0f;
#pragma unroll
        for (int i = 0; i < NW; ++i) s += red[i][rr][cc];
        out[((size_t)img * IMG + (i0 + rr)) * IMG + (j0 + cc)] = tanhf(s);
    }
}

extern "C" void kernel_launch(void* const* d_in, const int* in_sizes, int n_in,
                              void* d_out, int out_size, void* d_ws, size_t ws_size,
                              hipStream_t stream) {
    const float* pts  = (const float*)d_in[0];
    const int    nimg = in_sizes[0] / (NPTS * 3);   // 8
    float*       out  = (float*)d_out;

    const int blocks = nimg * 32;                   // 256: one block per out-tile
    plot_fused_kernel<<<blocks, dim3(512), 0, stream>>>(pts, out);
}

// Round 5
// 21.775 us; speedup vs baseline: 2.6004x; 1.3057x over previous
//
#include <hip/hip_runtime.h>
#include <hip/hip_bf16.h>
#include <cmath>

// PlotLine: 8 polylines -> 128x128 Gaussian-splatted images, tanh'd.
// draft[n,i,j] = sum_l exp(-(i-x_l)^2/2w_l) * exp(-(j-y_l)^2/2w_l); out = tanh.
// Single fused kernel, NO workspace. Block = one (img, 32x16 tile), full K.
// 8 waves split K; MFMA fragments built in registers:
//   raw v_exp_f32 (__builtin_amdgcn_exp2f), bf16 via +0x8000 + v_perm pack.

constexpr int IMG  = 128;
constexpr int NPTS = 32;
constexpr int TPL  = 181;           // samples per segment
constexpr int LTOT = 31 * TPL;      // 5611
constexpr int KC   = 32;            // K per MFMA chunk
constexpr int NCH  = 176;           // ceil(LTOT/KC): 176*32 = 5632 (tail padded)
constexpr int NW   = 8;             // waves per block
constexpr int CPW  = NCH / NW;      // 22 chunks per wave
constexpr int TI   = 32;            // tile rows (i)
constexpr int TJ   = 16;            // tile cols (j)

typedef __attribute__((ext_vector_type(8))) short bf16x8;
typedef __attribute__((ext_vector_type(4))) float f32x4;

__device__ inline float fast_exp2(float x) {
#if __has_builtin(__builtin_amdgcn_exp2f)
    return __builtin_amdgcn_exp2f(x);      // raw v_exp_f32; args <= 0 here
#else
    return exp2f(x);
#endif
}

__device__ inline float fast_rcp(float x) {
#if __has_builtin(__builtin_amdgcn_rcpf)
    return __builtin_amdgcn_rcpf(x);       // v_rcp_f32, ~1 ulp
#else
    return 1.0f / x;
#endif
}

// pack two positive f32 into bf16 pair (round-half-up): 2 adds + 1 v_perm
__device__ inline unsigned pack_bf16_pair(float lo, float hi) {
    unsigned ulo = __builtin_bit_cast(unsigned, lo) + 0x8000u;
    unsigned uhi = __builtin_bit_cast(unsigned, hi) + 0x8000u;
#if __has_builtin(__builtin_amdgcn_perm)
    return __builtin_amdgcn_perm(uhi, ulo, 0x07060302u);  // [ulo.hi16, uhi.hi16]
#else
    return (ulo >> 16) | (uhi & 0xFFFF0000u);
#endif
}

union Frag { bf16x8 v; unsigned u[4]; };

__global__ __launch_bounds__(512, 1)
void plot_fused_kernel(const float* __restrict__ pts, float* __restrict__ out)
{
    const int bx   = blockIdx.x;
    const int img  = bx >> 5;           // 32 tiles per image
    const int tile = bx & 31;
    const int i0   = (tile >> 3) * TI;  // 4 row-tiles
    const int j0   = (tile & 7) * TJ;   // 8 col-tiles

    const int t   = threadIdx.x;
    const int w   = t >> 6;             // wave 0..7
    const int lid = t & 63;

    __shared__ float4 ptsh[NPTS];           // (x, y, width, _)
    __shared__ float4 p4s[NW][KC];          // per-wave l-params: cf, B1x, C0x, B1y
    __shared__ float  c0ys[NW][KC];         // C0y
    __shared__ float  red[NW][TI][TJ + 2];  // epilogue partials (stride 18)

    if (t < NPTS) {
        const float* p = pts + (img * NPTS + t) * 3;
        ptsh[t] = make_float4(p[0], p[1], p[2], 0.0f);
    }
    __syncthreads();

    f32x4 acc0 = (f32x4)0.0f;   // rows i0..i0+15
    f32x4 acc1 = (f32x4)0.0f;   // rows i0+16..i0+31

    const float r0f = (float)(i0 + (lid & 15));
    const float r1f = r0f + 16.0f;
    const float cjf = (float)(j0 + (lid & 15));
    const float r02 = r0f * r0f;
    const float r12 = r1f * r1f;
    const float cj2 = cjf * cjf;
    const int   kb  = (lid >> 4) * 8;       // k base within chunk

    for (int tt = 0; tt < CPW; ++tt) {
        const int c = w + NW * tt;          // this wave's chunk (0..175)

        // ---- params: lanes 0..31 compute quadratic coeffs for l = c*32+lane.
        // exp arg = cf*(r-x)^2 = cf*r^2 + B1*r + C0   (2 FMA per element)
        if (lid < KC) {
            const int l = c * KC + lid;
            float cf = 0.0f, b1x = 0.0f, c0x = -1.0e30f, b1y = 0.0f, c0y = -1.0e30f;
            if (l < LTOT) {
                const int   seg = l / TPL;                  // magic-mul
                const float ft  = (float)(l - seg * TPL) * (1.0f / TPL);
                const float4 p0 = ptsh[seg];
                const float4 p1 = ptsh[seg + 1];
                const float x  = p0.x + ft * (p1.x - p0.x);
                const float y  = p0.y + ft * (p1.y - p0.y);
                const float wv = p0.z + ft * (p1.z - p0.z);
                cf  = -0.7213475204444817f * fast_rcp(wv);  // -log2(e)/(2w)
                b1x = -2.0f * cf * x;  c0x = cf * x * x;
                b1y = -2.0f * cf * y;  c0y = cf * y * y;
            }
            p4s[w][lid]  = make_float4(cf, b1x, c0x, b1y);
            c0ys[w][lid] = c0y;
        }
        // per-wave LDS, intra-wave producer->consumer: lgkmcnt orders it

        // ---- fragments in registers: 24 raw exps + 12 packs per lane
        Frag A0, A1, B0;
#pragma unroll
        for (int jp = 0; jp < 4; ++jp) {
            const float4 q0 = p4s[w][kb + 2 * jp];
            const float4 q1 = p4s[w][kb + 2 * jp + 1];
            const float  y0 = c0ys[w][kb + 2 * jp];
            const float  y1 = c0ys[w][kb + 2 * jp + 1];
            const float ea0 = fast_exp2(fmaf(q0.x, r02, fmaf(q0.y, r0f, q0.z)));
            const float eb0 = fast_exp2(fmaf(q1.x, r02, fmaf(q1.y, r0f, q1.z)));
            A0.u[jp] = pack_bf16_pair(ea0, eb0);
            const float ea1 = fast_exp2(fmaf(q0.x, r12, fmaf(q0.y, r1f, q0.z)));
            const float eb1 = fast_exp2(fmaf(q1.x, r12, fmaf(q1.y, r1f, q1.z)));
            A1.u[jp] = pack_bf16_pair(ea1, eb1);
            const float ec0 = fast_exp2(fmaf(q0.x, cj2, fmaf(q0.w, cjf, y0)));
            const float ec1 = fast_exp2(fmaf(q1.x, cj2, fmaf(q1.w, cjf, y1)));
            B0.u[jp] = pack_bf16_pair(ec0, ec1);
        }

        acc0 = __builtin_amdgcn_mfma_f32_16x16x32_bf16(A0.v, B0.v, acc0, 0, 0, 0);
        acc1 = __builtin_amdgcn_mfma_f32_16x16x32_bf16(A1.v, B0.v, acc1, 0, 0, 0);
    }

    // ---- epilogue: 8-wave K reduction via LDS, tanh, store
    // D layout: col = lane&15, row = (lane>>4)*4 + r   (verified round 2)
    const int drow = (lid >> 4) * 4;
    const int dcol = lid & 15;
#pragma unroll
    for (int r = 0; r < 4; ++r) {
        red[w][drow + r][dcol]      = acc0[r];
        red[w][16 + drow + r][dcol] = acc1[r];
    }
    __syncthreads();

    {
        const int rr = t >> 4;          // 0..31
        const int cc = t & 15;          // 0..15
        float s = 0.0f;
#pragma unroll
        for (int i = 0; i < NW; ++i) s += red[i][rr][cc];
        out[((size_t)img * IMG + (i0 + rr)) * IMG + (j0 + cc)] = tanhf(s);
    }
}

extern "C" void kernel_launch(void* const* d_in, const int* in_sizes, int n_in,
                              void* d_out, int out_size, void* d_ws, size_t ws_size,
                              hipStream_t stream) {
    const float* pts  = (const float*)d_in[0];
    const int    nimg = in_sizes[0] / (NPTS * 3);   // 8
    float*       out  = (float*)d_out;

    const int blocks = nimg * 32;                   // 256: one block per out-tile
    plot_fused_kernel<<<blocks, dim3(512), 0, stream>>>(pts, out);
}